// Round 1
// baseline (250.379 us; speedup 1.0000x reference)
//
#include <hip/hip_runtime.h>
#include <hip/hip_bf16.h>

#define NROWS 8192
#define DDIM 64

typedef __attribute__((ext_vector_type(8))) short short8v;
typedef __attribute__((ext_vector_type(4))) float f32x4;

__device__ __constant__ float d_TAU = 0.5f;
#define K2CONST 2.885390081777927f  /* log2(e)/TAU */
#define EPSC 1e-8f

// ---------------- Kernel 1: row L2-normalize + diagonals ----------------
__global__ __launch_bounds__(256) void k_normalize(
    const float* __restrict__ z, const float* __restrict__ za,
    float* __restrict__ zn, float* __restrict__ zan, __hip_bfloat16* __restrict__ Pb,
    float* __restrict__ dI1, float* __restrict__ dI2, float* __restrict__ dX) {
  int wid = (blockIdx.x * blockDim.x + threadIdx.x) >> 6;
  int lane = threadIdx.x & 63;
  if (wid >= NROWS) return;
  float x = z[wid * DDIM + lane];
  float y = za[wid * DDIM + lane];
  float sx = x * x, sy = y * y, sxy = x * y;
  for (int m = 1; m < 64; m <<= 1) {
    sx  += __shfl_xor(sx, m);
    sy  += __shfl_xor(sy, m);
    sxy += __shfl_xor(sxy, m);
  }
  float inx = 1.0f / fmaxf(sqrtf(sx), 1e-12f);
  float iny = 1.0f / fmaxf(sqrtf(sy), 1e-12f);
  float xn = x * inx, yn = y * iny;
  zn[wid * DDIM + lane] = xn;
  zan[wid * DDIM + lane] = yn;
  Pb[wid * DDIM + lane] = __float2bfloat16(xn);
  Pb[(NROWS + wid) * DDIM + lane] = __float2bfloat16(yn);
  if (lane == 0) {
    dI1[wid] = expf(sx * inx * inx * 2.0f);   // /TAU = *2
    dI2[wid] = expf(sy * iny * iny * 2.0f);
    dX[wid]  = expf(sxy * inx * iny * 2.0f);
  }
}

// ---------------- Kernel 2: dense exp-gram row sums via MFMA ----------------
// P = [zn; zan] (16384 x 64) bf16. For each row i of P accumulate
// sumA[i] = sum_{j<N} exp(P_i.P_j/tau), sumB[i] = sum_{j>=N} exp(...).
__global__ __launch_bounds__(256) void k_rowsums(
    const __hip_bfloat16* __restrict__ Pb,
    float* __restrict__ sumA, float* __restrict__ sumB) {
  int wave = threadIdx.x >> 6, lane = threadIdx.x & 63;
  int rowbase = blockIdx.x * 256 + wave * 64;  // 64 rows per wave (4 tiles of 16)
  int chunk = blockIdx.y;                      // 16 chunks of 1024 cols
  int colbase = chunk * 1024;
  float* bucket = (chunk < 8) ? sumA : sumB;
  const short8v* P8 = reinterpret_cast<const short8v*>(Pb);

  int r_in = lane & 15, kq = lane >> 4;
  short8v a0[4], a1[4];
#pragma unroll
  for (int rt = 0; rt < 4; rt++) {
    int row = rowbase + rt * 16 + r_in;
    a0[rt] = P8[row * 8 + kq];
    a1[rt] = P8[row * 8 + kq + 4];
  }
  f32x4 s[4];
#pragma unroll
  for (int rt = 0; rt < 4; rt++) s[rt] = (f32x4){0.f, 0.f, 0.f, 0.f};

  for (int ct = 0; ct < 64; ct++) {
    int crow = colbase + ct * 16 + r_in;
    short8v b0 = P8[crow * 8 + kq];
    short8v b1 = P8[crow * 8 + kq + 4];
#pragma unroll
    for (int rt = 0; rt < 4; rt++) {
      f32x4 acc = (f32x4){0.f, 0.f, 0.f, 0.f};
      acc = __builtin_amdgcn_mfma_f32_16x16x32_bf16(a0[rt], b0, acc, 0, 0, 0);
      acc = __builtin_amdgcn_mfma_f32_16x16x32_bf16(a1[rt], b1, acc, 0, 0, 0);
#pragma unroll
      for (int c = 0; c < 4; c++) s[rt][c] += exp2f(acc[c] * K2CONST);
    }
  }
  // reduce across the 16 lanes sharing the same kq (these span the 16 cols)
#pragma unroll
  for (int m = 1; m <= 8; m <<= 1) {
#pragma unroll
    for (int rt = 0; rt < 4; rt++) {
#pragma unroll
      for (int c = 0; c < 4; c++) s[rt][c] += __shfl_xor(s[rt][c], m);
    }
  }
  if (r_in == 0) {
#pragma unroll
    for (int rt = 0; rt < 4; rt++) {
#pragma unroll
      for (int c = 0; c < 4; c++) {
        int row = rowbase + rt * 16 + kq * 4 + c;
        atomicAdd(&bucket[row], s[rt][c]);
      }
    }
  }
}

// ---------------- Kernel 3: sparse adj-masked sums (stream adj once) -------
__global__ __launch_bounds__(256) void k_sparse(
    const float* __restrict__ adj, const float* __restrict__ adj_aug,
    const float* __restrict__ zn, const float* __restrict__ zan,
    float* __restrict__ sI, float* __restrict__ sJ, float* __restrict__ sC) {
  int wid = (blockIdx.x * blockDim.x + threadIdx.x) >> 6;
  int lane = threadIdx.x & 63;
  int m = wid >> 13;           // 0: (z, z_aug, adj), 1: (z_aug, z, adj_aug)
  int i = wid & (NROWS - 1);
  const float* A = m ? adj_aug : adj;
  const float* X = m ? zan : zn;  // intra partner (and own row source)
  const float* Y = m ? zn : zan;  // inter partner
  float a = X[i * DDIM + lane];
  const float4* rowp = reinterpret_cast<const float4*>(A + (size_t)i * NROWS);
  float accI = 0.f, accJ = 0.f, accC = 0.f;

  for (int c0 = 0; c0 < NROWS; c0 += 256) {
    float4 v = rowp[(c0 >> 2) + lane];
    bool nz = (v.x != 0.f) || (v.y != 0.f) || (v.z != 0.f) || (v.w != 0.f);
    unsigned long long mask = __ballot(nz);
    while (mask) {
      int src = __ffsll((unsigned long long)mask) - 1;
      mask &= (mask - 1);
      float v0 = __shfl(v.x, src), v1 = __shfl(v.y, src);
      float v2 = __shfl(v.z, src), v3 = __shfl(v.w, src);
      float vv[4] = {v0, v1, v2, v3};
      int jb = c0 + src * 4;
#pragma unroll
      for (int k = 0; k < 4; k++) {
        float av = vv[k];
        if (av != 0.f) {        // uniform across wave
          int j = jb + k;
          float p = X[j * DDIM + lane];
          float q = Y[j * DDIM + lane];
          float r1 = a * p, r2 = a * q;
          for (int mm = 1; mm < 64; mm <<= 1) {
            r1 += __shfl_xor(r1, mm);
            r2 += __shfl_xor(r2, mm);
          }
          accI += av * exp2f(r1 * K2CONST);
          accJ += av * exp2f(r2 * K2CONST);
          accC += av;
        }
      }
    }
  }
  if (lane == 0) {
    sI[m * NROWS + i] = accI;
    sJ[m * NROWS + i] = accJ;
    sC[m * NROWS + i] = accC;
  }
}

// ---------------- Kernel 4: per-row loss + mean ----------------
__global__ __launch_bounds__(256) void k_final(
    const float* __restrict__ sumA, const float* __restrict__ sumB,
    const float* __restrict__ dI1, const float* __restrict__ dI2,
    const float* __restrict__ dX,
    const float* __restrict__ sI, const float* __restrict__ sJ,
    const float* __restrict__ sC, float* __restrict__ out) {
  float local = 0.f;
  for (int i = threadIdx.x; i < NROWS; i += 256) {
    // call 1: (z, z_aug, adj). Row i of P: bucketA = intra1, bucketB = inter1
    float pos1 = dX[i] + sI[i] + sJ[i];
    float den1 = sumA[i] + sumB[i] - dI1[i];
    float l1 = logf(pos1 / (den1 + EPSC) + EPSC) / (2.0f * sC[i] + 1.0f);
    // call 2: (z_aug, z, adj_aug). Row N+i: bucketA = inter2, bucketB = intra2
    float pos2 = dX[i] + sI[NROWS + i] + sJ[NROWS + i];
    float den2 = sumA[NROWS + i] + sumB[NROWS + i] - dI2[i];
    float l2 = logf(pos2 / (den2 + EPSC) + EPSC) / (2.0f * sC[NROWS + i] + 1.0f);
    local += l1 + l2;
  }
  for (int m = 1; m < 64; m <<= 1) local += __shfl_xor(local, m);
  __shared__ float red[4];
  if ((threadIdx.x & 63) == 0) red[threadIdx.x >> 6] = local;
  __syncthreads();
  if (threadIdx.x == 0) {
    float t = red[0] + red[1] + red[2] + red[3];
    out[0] = -t * (0.5f / (float)NROWS);
  }
}

extern "C" void kernel_launch(void* const* d_in, const int* in_sizes, int n_in,
                              void* d_out, int out_size, void* d_ws, size_t ws_size,
                              hipStream_t stream) {
  const float* z       = (const float*)d_in[0];
  const float* za      = (const float*)d_in[1];
  const float* adj     = (const float*)d_in[2];
  const float* adj_aug = (const float*)d_in[3];

  float* ws = (float*)d_ws;
  float* zn  = ws;                          // 524288 f32
  float* zan = ws + 524288;                 // 524288 f32
  __hip_bfloat16* Pb = (__hip_bfloat16*)(ws + 1048576);  // 1048576 bf16 (=524288 f32 slots)
  float* sumA = ws + 1572864;               // 16384
  float* sumB = sumA + 16384;               // 16384
  float* dI1  = sumB + 16384;               // 8192
  float* dI2  = dI1 + 8192;                 // 8192
  float* dX   = dI2 + 8192;                 // 8192
  float* sI   = dX + 8192;                  // 16384
  float* sJ   = sI + 16384;                 // 16384
  float* sC   = sJ + 16384;                 // 16384

  hipMemsetAsync(sumA, 0, 32768 * sizeof(float), stream);

  k_normalize<<<2048, 256, 0, stream>>>(z, za, zn, zan, Pb, dI1, dI2, dX);
  dim3 g2(64, 16);
  k_rowsums<<<g2, 256, 0, stream>>>(Pb, sumA, sumB);
  k_sparse<<<4096, 256, 0, stream>>>(adj, adj_aug, zn, zan, sI, sJ, sC);
  k_final<<<1, 256, 0, stream>>>(sumA, sumB, dI1, dI2, dX, sI, sJ, sC, (float*)d_out);
}